// Round 9
// baseline (274.206 us; speedup 1.0000x reference)
//
#include <hip/hip_runtime.h>
#include <hip/hip_bf16.h>
#include <math.h>

#define B_ 8
#define S_ 2048
#define D_ 1024
#define H_ 64
#define M_ (B_*S_)
#define SPLIT 4
#define KPS (S_/SPLIT)   // 512 keys per split

typedef __attribute__((ext_vector_type(8))) short bf16x8;
typedef __attribute__((ext_vector_type(8))) unsigned short u16x8;
typedef __attribute__((ext_vector_type(4))) float f32x4;

__device__ inline unsigned short f2bf(float f) {
    unsigned int u = __builtin_bit_cast(unsigned int, f);
    u += 0x7fffu + ((u >> 16) & 1u);   // round-to-nearest-even
    return (unsigned short)(u >> 16);
}

// async global->LDS, 16B per lane (global side carries any swizzle).
__device__ inline void async16(const void* g, void* l) {
    __builtin_amdgcn_global_load_lds((const __attribute__((address_space(1))) void*)g,
                                     (__attribute__((address_space(3))) void*)l, 16, 0, 0);
}

// mask -> multiplicative 1.0/0.0. Layout sniff: jax bool may be 1-byte or int32.
__global__ __launch_bounds__(256) void mask_kernel(const unsigned char* __restrict__ mask,
                                                   float* __restrict__ mmul, int n) {
    int j = blockIdx.x * 256 + threadIdx.x;
    if (j >= n) return;
    bool boolLayout = mask[1] != 0;
    int mv = boolLayout ? (int)mask[j] : ((const int*)mask)[j];
    mmul[j] = mv ? 1.0f : 0.0f;
}

// Transpose W[1024][64] fp32 -> Wt[64][1024] bf16, one matrix per blockIdx.y.
__global__ __launch_bounds__(256) void wprep_kernel(
    const float* __restrict__ Wq, const float* __restrict__ Wk, const float* __restrict__ Wv,
    unsigned short* __restrict__ Wt)
{
    const int m = blockIdx.y;
    const float* W = (m == 0) ? Wq : (m == 1) ? Wk : Wv;
    unsigned short* Wo = Wt + (size_t)m * 64 * 1024;
    __shared__ unsigned short T[64][65];
    const int t = threadIdx.x;
    const int k0 = blockIdx.x * 64;
    #pragma unroll
    for (int i = 0; i < 16; i++) {
        int vi = t + i * 256;
        int kk = vi >> 6, n = vi & 63;
        T[kk][n] = f2bf(W[(size_t)(k0 + kk) * 64 + n]);
    }
    __syncthreads();
    #pragma unroll
    for (int i = 0; i < 4; i++) {
        int vi = t + i * 256;
        int n = vi >> 4, k4 = vi & 15;
        ushort4 u;
        u.x = T[k4*4+0][n]; u.y = T[k4*4+1][n]; u.z = T[k4*4+2][n]; u.w = T[k4*4+3][n];
        *(ushort4*)&Wo[(size_t)n * 1024 + k0 + k4*4] = u;
    }
}

// x[M,1024] @ W[1024,64].
// Round-8 ledger: 7 structurally different projs (traffic 300-603MB,
// barriers 8-32, conflicts 0-1.6M, occ 10-28%) ALL land 80-95us. The one
// invariant: every variant read each 4KB x-row in 16-32 visits of <=256B
// (k-sliced staging). Small strided re-visits thrash DRAM pages / channel
// spread; the 6.3TB/s copy reads each page once, sequentially. This version
// tests the large-visit cell:
//   * Segment K=256: A stage = 64 rows x 1KB CONTIGUOUS per row. One
//     global_load_lds covers one full 1KB row-segment (64 lanes x 16B,
//     lane-permuted by XOR involution). 4 visits/row of 1KB, vs 16-32 small.
//   * LDS[row][l] = global_unit[l ^ row]; read slot vu^arow -> same-quad
//     lanes hit 16 distinct slots mod 16 => 2-way max bank alias (free).
//   * A double-buffered 2x64KB = 128KB LDS, 1 block/CU (occupancy proven
//     irrelevant across R4-R8). B read R1-style straight from global into
//     registers (L2/L3-resident 384KB; R1 proved perf-neutral).
//   * 2 barriers/segment (8 total): own-stage vmcnt(16) certification at
//     top (16 younger = next stage's insts), reuse barrier after compute.
//     vmcnt(0) only at the tail.
__global__ __launch_bounds__(256) void proj_kernel(
    const float* __restrict__ q, const float* __restrict__ kx, const float* __restrict__ vx,
    const unsigned short* __restrict__ Wt,
    unsigned short* __restrict__ qp, unsigned short* __restrict__ kp, unsigned short* __restrict__ vpT)
{
    __shared__ float As[2][64 * 256];   // [buf][row*256 + slot*4] 64KB each

    const int m = blockIdx.y;
    const float* x = (m == 0) ? q : (m == 1) ? kx : vx;
    const unsigned short* Wm = Wt + (size_t)m * 64 * 1024;

    const int t = threadIdx.x;
    const int w = t >> 6, l = t & 63;
    const int lrow = l & 15, quad = l >> 4;
    const int row0 = blockIdx.x * 64;
    const int arow = w * 16 + lrow;     // this wave's A row (0..63)

    f32x4 acc[4] = {};

    // One inst = one full 1KB row-segment: inst j of wave w covers row j*4+w,
    // lane l writes LDS slot l from global unit (l ^ row) of that row's
    // [s*1KB, s*1KB+1KB) span. 16 insts/thread per segment.
#define STAGE(s, Ad) do { \
    _Pragma("unroll") \
    for (int j_ = 0; j_ < 16; j_++) { \
        const int row_ = j_ * 4 + w; \
        async16(x + (size_t)(row0 + row_) * D_ + (s) * 256 + ((l ^ row_) << 2), \
                (Ad) + row_ * 256 + l * 4); \
    } \
    asm volatile("" ::: "memory"); } while (0)

    // 8 k-chunks of 32; A from LDS (slot = vu ^ arow), B from global (L2-hit).
#define COMPUTE(Aa, s) do { \
    _Pragma("unroll") \
    for (int kc_ = 0; kc_ < 8; kc_++) { \
        const int vu_ = kc_ * 8 + quad * 2; \
        f32x4 a0_ = *(const f32x4*)&(Aa)[arow * 256 + (((vu_    ) ^ arow)) * 4]; \
        f32x4 a1_ = *(const f32x4*)&(Aa)[arow * 256 + (((vu_ + 1) ^ arow)) * 4]; \
        bf16x8 af_; \
        af_[0] = (short)f2bf(a0_.x); af_[1] = (short)f2bf(a0_.y); \
        af_[2] = (short)f2bf(a0_.z); af_[3] = (short)f2bf(a0_.w); \
        af_[4] = (short)f2bf(a1_.x); af_[5] = (short)f2bf(a1_.y); \
        af_[6] = (short)f2bf(a1_.z); af_[7] = (short)f2bf(a1_.w); \
        _Pragma("unroll") \
        for (int c_ = 0; c_ < 4; c_++) { \
            bf16x8 b_ = *(const bf16x8*)&Wm[(size_t)(c_ * 16 + lrow) * 1024 \
                                            + (s) * 256 + kc_ * 32 + quad * 8]; \
            acc[c_] = __builtin_amdgcn_mfma_f32_16x16x32_bf16(af_, b_, acc[c_], 0, 0, 0); \
        } \
    } } while (0)

#define WAIT16 asm volatile("s_waitcnt vmcnt(16)\n\ts_barrier" ::: "memory")
#define WAIT0  asm volatile("s_waitcnt vmcnt(0)\n\ts_barrier" ::: "memory")
#define REUSE_BAR asm volatile("s_barrier" ::: "memory")

    float* A0 = &As[0][0];
    float* A1 = &As[1][0];

    STAGE(0, A0);
    STAGE(1, A1);
    // s=0: 16 younger (stage 1) remain -> stage 0 + anything older drained
    WAIT16; COMPUTE(A0, 0); REUSE_BAR; STAGE(2, A0);
    // s=1: 16 younger (stage 2) remain -> stage 1 + B leftovers drained
    WAIT16; COMPUTE(A1, 1); REUSE_BAR; STAGE(3, A1);
    // s=2: 16 younger (stage 3) remain -> stage 2 drained; no re-stage needed
    WAIT16; COMPUTE(A0, 2); REUSE_BAR;
    // s=3: full drain
    WAIT0;  COMPUTE(A1, 3);

#undef STAGE
#undef COMPUTE
#undef WAIT16
#undef WAIT0
#undef REUSE_BAR

    const int orow = row0 + w * 16 + quad * 4;
    if (m < 2) {
        unsigned short* outp = (m == 0) ? qp : kp;
        const float sc = (m == 0) ? 0.125f : 1.0f;   // fold attn scale into qp
        #pragma unroll
        for (int c = 0; c < 4; c++)
            #pragma unroll
            for (int rr = 0; rr < 4; rr++)
                outp[(size_t)(orow + rr) * H_ + c * 16 + lrow] = f2bf(acc[c][rr] * sc);
    } else {
        // vpT[b][h][s], s0..s0+3 contiguous per lane -> 8B stores
        const int bb = orow >> 11;
        const int s0 = orow & (S_ - 1);
        #pragma unroll
        for (int c = 0; c < 4; c++) {
            ushort4 u;
            u.x = f2bf(acc[c][0]); u.y = f2bf(acc[c][1]);
            u.z = f2bf(acc[c][2]); u.w = f2bf(acc[c][3]);
            *(ushort4*)&vpT[((size_t)bb * H_ + c * 16 + lrow) * S_ + s0] = u;
        }
    }
}

// Flash attention partial: block = (q-tile 64, batch, key-split). Max-free
// single-pass exp => partials over disjoint key ranges combine by addition.
// K and V^T tiles async-staged (L2-resident -> cheap barrier drain).
__global__ __launch_bounds__(256) void attn_kernel(
    const unsigned short* __restrict__ qp, const unsigned short* __restrict__ kp,
    const unsigned short* __restrict__ vpT, const float* __restrict__ mmul,
    float* __restrict__ po, float* __restrict__ pl)
{
    __shared__ unsigned short Qs[64][72];
    __shared__ unsigned short Ps[64][72];
    __shared__ unsigned short Ks[64 * 64];   // swizzled chunks [key][h]
    __shared__ unsigned short Vt[64 * 64];   // swizzled chunks [h][key]

    const int t = threadIdx.x;
    const int w = t >> 6, l = t & 63;
    const int lrow = l & 15, quad = l >> 4;
    const int b = blockIdx.y, q0 = blockIdx.x * 64, split = blockIdx.z;
    const int key0 = split * KPS;
    const size_t basebs = (size_t)b * S_;
    const unsigned short* vb = vpT + (size_t)b * H_ * S_;

    #pragma unroll
    for (int i = 0; i < 2; i++) {            // Q tile once: 512 16B-chunks
        int p = t + i * 256;
        int r = p >> 3, c8 = p & 7;
        u16x8 u = *(const u16x8*)&qp[(basebs + q0 + r) * H_ + c8 * 8];
        *(u16x8*)&Qs[r][c8 * 8] = u;
    }

    float lsum[4] = {0.f, 0.f, 0.f, 0.f};
    f32x4 o[4] = {};

    for (int kt = 0; kt < KPS / 64; kt++) {
        const int k0 = key0 + kt * 64;
        __syncthreads();                     // prev tile's LDS reads done
        #pragma unroll
        for (int j = 0; j < 2; j++) {        // K tile: 512 chunks
            int p = (w * 2 + j) * 64 + l;
            int r = p >> 3;
            int c8 = (p & 7) ^ (r & 7);
            async16(&kp[(basebs + k0 + r) * H_ + c8 * 8], &Ks[p * 8]);
        }
        #pragma unroll
        for (int j = 0; j < 2; j++) {        // V^T tile: 512 chunks
            int p = (w * 2 + j) * 64 + l;
            int h = p >> 3;
            int c8 = (p & 7) ^ (h & 7);
            async16(&vb[(size_t)h * S_ + k0 + c8 * 8], &Vt[p * 8]);
        }
        float mm[4];
        #pragma unroll
        for (int c = 0; c < 4; c++) mm[c] = mmul[basebs + k0 + c*16 + lrow];
        __syncthreads();                     // drain async queue

        // S = Q K^T (pre-scaled by 1/8 via qp)
        f32x4 s[4] = {};
        #pragma unroll
        for (int kk = 0; kk < 2; kk++) {
            bf16x8 aq = *(const bf16x8*)&Qs[w*16 + lrow][kk*32 + quad*8];
            #pragma unroll
            for (int c = 0; c < 4; c++) {
                const int n = c*16 + lrow;
                bf16x8 bk = *(const bf16x8*)&Ks[(n * 8 + ((kk*4 + quad) ^ (n & 7))) * 8];
                s[c] = __builtin_amdgcn_mfma_f32_16x16x32_bf16(aq, bk, s[c], 0, 0, 0);
            }
        }
        // single-pass softmax numerator; sum deferred
        #pragma unroll
        for (int r = 0; r < 4; r++) {
            float p0 = __expf(s[0][r]) * mm[0];
            float p1 = __expf(s[1][r]) * mm[1];
            float p2 = __expf(s[2][r]) * mm[2];
            float p3 = __expf(s[3][r]) * mm[3];
            lsum[r] += (p0 + p1) + (p2 + p3);
            const int pr = w*16 + quad*4 + r;
            Ps[pr][ 0 + lrow] = f2bf(p0);
            Ps[pr][16 + lrow] = f2bf(p1);
            Ps[pr][32 + lrow] = f2bf(p2);
            Ps[pr][48 + lrow] = f2bf(p3);
        }
        // Ps rows [w*16, w*16+16) wave-local: no barrier needed
        #pragma unroll
        for (int kk = 0; kk < 2; kk++) {
            bf16x8 ap = *(const bf16x8*)&Ps[w*16 + lrow][kk*32 + quad*8];
            #pragma unroll
            for (int c = 0; c < 4; c++) {
                const int h = c*16 + lrow;
                bf16x8 bv = *(const bf16x8*)&Vt[(h * 8 + ((kk*4 + quad) ^ (h & 7))) * 8];
                o[c] = __builtin_amdgcn_mfma_f32_16x16x32_bf16(ap, bv, o[c], 0, 0, 0);
            }
        }
    }

    float* pob = po + (size_t)split * M_ * H_;
    float* plb = pl + (size_t)split * M_;
    #pragma unroll
    for (int r = 0; r < 4; r++) {
        #pragma unroll
        for (int d = 1; d < 16; d <<= 1)
            lsum[r] += __shfl_xor(lsum[r], d, 64);
        const size_t row = basebs + q0 + w*16 + quad*4 + r;
        if (lrow == 0) plb[row] = lsum[r];
        #pragma unroll
        for (int c = 0; c < 4; c++)
            pob[row * H_ + c*16 + lrow] = o[c][r];
    }
}

// out = (sum_s po[s]) / (sum_s pl[s]); one float4 per thread.
__global__ __launch_bounds__(256) void combine_kernel(
    const float* __restrict__ po, const float* __restrict__ pl, float* __restrict__ out)
{
    const int idx = blockIdx.x * 256 + threadIdx.x;
    const size_t row = idx >> 4;
    const int c4 = (idx & 15) * 4;
    float lt = 0.f;
    #pragma unroll
    for (int s = 0; s < SPLIT; s++) lt += pl[(size_t)s * M_ + row];
    f32x4 acc = {};
    #pragma unroll
    for (int s = 0; s < SPLIT; s++) {
        const f32x4 p = *(const f32x4*)&po[((size_t)s * M_ + row) * H_ + c4];
        acc += p;
    }
    const float inv = 1.0f / lt;
    f32x4 r = acc * inv;
    *(f32x4*)&out[row * H_ + c4] = r;
}

extern "C" void kernel_launch(void* const* d_in, const int* in_sizes, int n_in,
                              void* d_out, int out_size, void* d_ws, size_t ws_size,
                              hipStream_t stream) {
    const float* q  = (const float*)d_in[0];
    const float* k  = (const float*)d_in[1];
    const float* v  = (const float*)d_in[2];
    const unsigned char* mask = (const unsigned char*)d_in[3];
    const float* Wq = (const float*)d_in[4];
    const float* Wk = (const float*)d_in[5];
    const float* Wv = (const float*)d_in[6];
    float* out = (float*)d_out;

    unsigned short* qp  = (unsigned short*)d_ws;         // 2 MB
    unsigned short* kp  = qp + (size_t)M_ * H_;          // 2 MB
    unsigned short* vpT = kp + (size_t)M_ * H_;          // 2 MB, [b][h][s]
    float* mmul = (float*)(vpT + (size_t)M_ * H_);       // 64 KB
    unsigned short* Wt = (unsigned short*)(mmul + M_);   // 384 KB
    float* po = (float*)(Wt + (size_t)3 * 64 * 1024);    // 16.8 MB
    float* pl = po + (size_t)SPLIT * M_ * H_;            // 256 KB

    wprep_kernel<<<dim3(16, 3), dim3(256), 0, stream>>>(Wq, Wk, Wv, Wt);
    mask_kernel<<<dim3((M_ + 255)/256), dim3(256), 0, stream>>>(mask, mmul, M_);
    proj_kernel<<<dim3(M_/64, 3), dim3(256), 0, stream>>>(q, k, v, Wt, qp, kp, vpT);
    attn_kernel<<<dim3(S_/64, B_, SPLIT), dim3(256), 0, stream>>>(qp, kp, vpT, mmul, po, pl);
    combine_kernel<<<dim3(M_*16/256), dim3(256), 0, stream>>>(po, pl, out);
}

// Round 10
// 257.786 us; speedup vs baseline: 1.0637x; 1.0637x over previous
//
#include <hip/hip_runtime.h>
#include <hip/hip_bf16.h>
#include <math.h>

#define B_ 8
#define S_ 2048
#define D_ 1024
#define H_ 64
#define M_ (B_*S_)
#define SPLIT 4          // attn key-splits
#define KPS (S_/SPLIT)   // 512 keys per split
#define SPLITK 2         // proj K-splits
#define KSEG (D_/SPLITK) // 512 k per proj block = 16 chunks of 32

typedef __attribute__((ext_vector_type(8))) short bf16x8;
typedef __attribute__((ext_vector_type(8))) unsigned short u16x8;
typedef __attribute__((ext_vector_type(4))) float f32x4;

__device__ inline unsigned short f2bf(float f) {
    unsigned int u = __builtin_bit_cast(unsigned int, f);
    u += 0x7fffu + ((u >> 16) & 1u);   // round-to-nearest-even
    return (unsigned short)(u >> 16);
}

// async global->LDS, 16B per lane (global side carries any swizzle).
__device__ inline void async16(const void* g, void* l) {
    __builtin_amdgcn_global_load_lds((const __attribute__((address_space(1))) void*)g,
                                     (__attribute__((address_space(3))) void*)l, 16, 0, 0);
}

// mask -> multiplicative 1.0/0.0. Layout sniff: jax bool may be 1-byte or int32.
__global__ __launch_bounds__(256) void mask_kernel(const unsigned char* __restrict__ mask,
                                                   float* __restrict__ mmul, int n) {
    int j = blockIdx.x * 256 + threadIdx.x;
    if (j >= n) return;
    bool boolLayout = mask[1] != 0;
    int mv = boolLayout ? (int)mask[j] : ((const int*)mask)[j];
    mmul[j] = mv ? 1.0f : 0.0f;
}

// Transpose W[1024][64] fp32 -> Wt[64][1024] bf16, one matrix per blockIdx.y.
__global__ __launch_bounds__(256) void wprep_kernel(
    const float* __restrict__ Wq, const float* __restrict__ Wk, const float* __restrict__ Wv,
    unsigned short* __restrict__ Wt)
{
    const int m = blockIdx.y;
    const float* W = (m == 0) ? Wq : (m == 1) ? Wk : Wv;
    unsigned short* Wo = Wt + (size_t)m * 64 * 1024;
    __shared__ unsigned short T[64][65];
    const int t = threadIdx.x;
    const int k0 = blockIdx.x * 64;
    #pragma unroll
    for (int i = 0; i < 16; i++) {
        int vi = t + i * 256;
        int kk = vi >> 6, n = vi & 63;
        T[kk][n] = f2bf(W[(size_t)(k0 + kk) * 64 + n]);
    }
    __syncthreads();
    #pragma unroll
    for (int i = 0; i < 4; i++) {
        int vi = t + i * 256;
        int n = vi >> 4, k4 = vi & 15;
        ushort4 u;
        u.x = T[k4*4+0][n]; u.y = T[k4*4+1][n]; u.z = T[k4*4+2][n]; u.w = T[k4*4+3][n];
        *(ushort4*)&Wo[(size_t)n * 1024 + k0 + k4*4] = u;
    }
}

// x[M,1024] @ W[1024,64], K-SPLIT partial GEMM.
// Round-9 ledger across 8 variants: duration tracks resident waves/CU
// monotonically (12 waves -> 80-85us, 8 -> 87, 4 -> 95-114) and NOTHING
// else (traffic 300-603MB, barriers 8-32, conflicts 0-1.6M, visit size
// 128B-1KB all moved nothing at fixed occupancy). Diagnosis: latency x TLP
// bound (~900cy HBM latency); the GRID (768 blocks = 12 waves/CU) caps TLP
// -- the one variable never changed. Fix: blockIdx.z splits K in half ->
// 1536 blocks = 24 waves/CU. Each block computes an fp32 PARTIAL over
// K=512 (disjoint reads; partials sum in cproj). Core schedule = R4's
// proven-fastest chunk pipeline: 16 chunks of 32, quad-buffered B staging,
// uniform own-count vmcnt(8)+barrier (certifies B(kc)+A(kc): exactly 8
// younger vmem insts), counted tail 6/3/0.
__global__ __launch_bounds__(256) void proj_kernel(
    const float* __restrict__ q, const float* __restrict__ kx, const float* __restrict__ vx,
    const unsigned short* __restrict__ Wt,
    float* __restrict__ pp)
{
    __shared__ unsigned short Bb[4][64 * 32];   // 4 x 4KB chunk buffers

    const int m = blockIdx.y;
    const int ks = blockIdx.z;
    const float* x = (m == 0) ? q : (m == 1) ? kx : vx;
    const unsigned short* Wm = Wt + (size_t)m * 64 * 1024;
    const int kbase = ks * KSEG;

    const int t = threadIdx.x;
    const int w = t >> 6, l = t & 63;
    const int lrow = l & 15, quad = l >> 4;
    const int row0 = blockIdx.x * 64;

    // A stream: row = row0 + w*16 + lrow, k-offset quad*8 within each 32-chunk
    const float* xa = x + (size_t)(row0 + w * 16 + lrow) * D_ + kbase + quad * 8;
    // B stage: thread t -> row n = t>>2, 16B unit u = t&3; source k pre-swizzled.
    const int bn = t >> 2, bu = t & 3;
    const unsigned short* wsrc = Wm + (size_t)bn * 1024 + kbase + (bu ^ (bn & 3)) * 8;
    // B read: slot = quad ^ (n&3); n&3 == lrow&3 for all col-blocks
    const int runit = (quad ^ (lrow & 3)) * 8;

    f32x4 acc[4] = {};
    f32x4 pa0[4], pa1[4];

#define ISSUE_B(kc, buf) do { \
    async16(wsrc + (kc) * 32, &Bb[buf][t * 8]); \
    asm volatile("" ::: "memory"); } while (0)

#define LOAD_A(st, kc) do { \
    pa0[st] = *(const f32x4*)(xa + (kc) * 32); \
    pa1[st] = *(const f32x4*)(xa + (kc) * 32 + 4); \
    asm volatile("" ::: "memory"); } while (0)

#define COMPUTE(st, buf) do { \
    f32x4 a0_ = pa0[st], a1_ = pa1[st]; \
    bf16x8 af_; \
    af_[0] = (short)f2bf(a0_.x); af_[1] = (short)f2bf(a0_.y); \
    af_[2] = (short)f2bf(a0_.z); af_[3] = (short)f2bf(a0_.w); \
    af_[4] = (short)f2bf(a1_.x); af_[5] = (short)f2bf(a1_.y); \
    af_[6] = (short)f2bf(a1_.z); af_[7] = (short)f2bf(a1_.w); \
    bf16x8 b0_ = *(const bf16x8*)&Bb[buf][0 * 512 + lrow * 32 + runit]; \
    bf16x8 b1_ = *(const bf16x8*)&Bb[buf][1 * 512 + lrow * 32 + runit]; \
    bf16x8 b2_ = *(const bf16x8*)&Bb[buf][2 * 512 + lrow * 32 + runit]; \
    bf16x8 b3_ = *(const bf16x8*)&Bb[buf][3 * 512 + lrow * 32 + runit]; \
    acc[0] = __builtin_amdgcn_mfma_f32_16x16x32_bf16(af_, b0_, acc[0], 0, 0, 0); \
    acc[1] = __builtin_amdgcn_mfma_f32_16x16x32_bf16(af_, b1_, acc[1], 0, 0, 0); \
    acc[2] = __builtin_amdgcn_mfma_f32_16x16x32_bf16(af_, b2_, acc[2], 0, 0, 0); \
    acc[3] = __builtin_amdgcn_mfma_f32_16x16x32_bf16(af_, b3_, acc[3], 0, 0, 0); } while (0)

#define W8 asm volatile("s_waitcnt vmcnt(8)\n\ts_barrier" ::: "memory")
#define W6 asm volatile("s_waitcnt vmcnt(6)\n\ts_barrier" ::: "memory")
#define W3 asm volatile("s_waitcnt vmcnt(3)\n\ts_barrier" ::: "memory")
#define W0 asm volatile("s_waitcnt vmcnt(0)\n\ts_barrier" ::: "memory")

    // prologue (order pinned): B0 A0 B1 A1 B2 A2 A3 = 11 vmem insts
    ISSUE_B(0, 0); LOAD_A(0, 0);
    ISSUE_B(1, 1); LOAD_A(1, 1);
    ISSUE_B(2, 2); LOAD_A(2, 2);
    LOAD_A(3, 3);

    // kc=0: vmcnt(8) leaves newest 8 -> B0,A0 done (8 insts follow A0)
    W8; ISSUE_B(3, 3);  COMPUTE(0, 0); LOAD_A(0, 4);
    // kc = 1..8
    #pragma unroll 1
    for (int ob = 0; ob < 2; ++ob) {
        #pragma unroll
        for (int kk = 0; kk < 4; ++kk) {
            const int kc = ob * 4 + kk + 1;
            const int st = (kk + 1) & 3;          // == kc&3
            W8; ISSUE_B(kc + 3, (st + 3) & 3); COMPUTE(st, st); LOAD_A(st, kc + 4);
        }
    }
    // kc = 9,10,11
    W8; ISSUE_B(12, 0); COMPUTE(1, 1); LOAD_A(1, 13);
    W8; ISSUE_B(13, 1); COMPUTE(2, 2); LOAD_A(2, 14);
    W8; ISSUE_B(14, 2); COMPUTE(3, 3); LOAD_A(3, 15);
    // kc = 12 (last B issue)
    W8; ISSUE_B(15, 3); COMPUTE(0, 0);
    // kc = 13,14,15: counted tail
    W6; COMPUTE(1, 1);
    W3; COMPUTE(2, 2);
    W0; COMPUTE(3, 3);

#undef ISSUE_B
#undef LOAD_A
#undef COMPUTE
#undef W8
#undef W6
#undef W3
#undef W0

    // fp32 partial store: pp[m][ks][row][col]; scale folded (linear in sum)
    const float sc = (m == 0) ? 0.125f : 1.0f;
    float* ppb = pp + ((size_t)(m * SPLITK + ks) * M_ + row0) * 64;
    const int orow = w * 16 + quad * 4;
    #pragma unroll
    for (int c = 0; c < 4; c++)
        #pragma unroll
        for (int rr = 0; rr < 4; rr++)
            ppb[(size_t)(orow + rr) * 64 + c * 16 + lrow] = acc[c][rr] * sc;
}

// Sum SPLITK partials, convert bf16, write qp/kp (row-major) and vpT
// (transposed [b][h][s] via LDS tile). Reads 25MB (L2/L3-warm) + 6MB write.
__global__ __launch_bounds__(256) void cproj_kernel(
    const float* __restrict__ pp,
    unsigned short* __restrict__ qp, unsigned short* __restrict__ kp,
    unsigned short* __restrict__ vpT)
{
    __shared__ unsigned short T[64][65];
    const int m = blockIdx.y;
    const int r0 = blockIdx.x * 64;
    const int t = threadIdx.x;
    const float* p0 = pp + ((size_t)(m * SPLITK + 0) * M_ + r0) * 64;
    const float* p1 = pp + ((size_t)(m * SPLITK + 1) * M_ + r0) * 64;

    if (m < 2) {
        unsigned short* outp = (m == 0) ? qp : kp;
        #pragma unroll
        for (int i = 0; i < 4; i++) {
            int p = i * 256 + t;
            int row = p >> 4, qd = p & 15;
            f32x4 a = *(const f32x4*)&p0[(size_t)row * 64 + qd * 4];
            f32x4 b = *(const f32x4*)&p1[(size_t)row * 64 + qd * 4];
            f32x4 s = a + b;
            ushort4 u;
            u.x = f2bf(s.x); u.y = f2bf(s.y); u.z = f2bf(s.z); u.w = f2bf(s.w);
            *(ushort4*)&outp[(size_t)(r0 + row) * H_ + qd * 4] = u;
        }
    } else {
        #pragma unroll
        for (int i = 0; i < 4; i++) {
            int p = i * 256 + t;
            int row = p >> 4, qd = p & 15;
            f32x4 a = *(const f32x4*)&p0[(size_t)row * 64 + qd * 4];
            f32x4 b = *(const f32x4*)&p1[(size_t)row * 64 + qd * 4];
            f32x4 s = a + b;
            T[row][qd*4+0] = f2bf(s.x); T[row][qd*4+1] = f2bf(s.y);
            T[row][qd*4+2] = f2bf(s.z); T[row][qd*4+3] = f2bf(s.w);
        }
        __syncthreads();
        const int bb = r0 >> 11;            // batch (64 | 2048)
        const int s0 = r0 & (S_ - 1);
        #pragma unroll
        for (int i = 0; i < 4; i++) {
            int p = i * 256 + t;
            int h = p >> 4, sq = p & 15;
            ushort4 u;
            u.x = T[sq*4+0][h]; u.y = T[sq*4+1][h];
            u.z = T[sq*4+2][h]; u.w = T[sq*4+3][h];
            *(ushort4*)&vpT[((size_t)bb * H_ + h) * S_ + s0 + sq*4] = u;
        }
    }
}

// Flash attention partial: block = (q-tile 64, batch, key-split). Max-free
// single-pass exp => partials over disjoint key ranges combine by addition.
// K and V^T tiles async-staged (L2-resident -> cheap barrier drain).
__global__ __launch_bounds__(256) void attn_kernel(
    const unsigned short* __restrict__ qp, const unsigned short* __restrict__ kp,
    const unsigned short* __restrict__ vpT, const float* __restrict__ mmul,
    float* __restrict__ po, float* __restrict__ pl)
{
    __shared__ unsigned short Qs[64][72];
    __shared__ unsigned short Ps[64][72];
    __shared__ unsigned short Ks[64 * 64];   // swizzled chunks [key][h]
    __shared__ unsigned short Vt[64 * 64];   // swizzled chunks [h][key]

    const int t = threadIdx.x;
    const int w = t >> 6, l = t & 63;
    const int lrow = l & 15, quad = l >> 4;
    const int b = blockIdx.y, q0 = blockIdx.x * 64, split = blockIdx.z;
    const int key0 = split * KPS;
    const size_t basebs = (size_t)b * S_;
    const unsigned short* vb = vpT + (size_t)b * H_ * S_;

    #pragma unroll
    for (int i = 0; i < 2; i++) {            // Q tile once: 512 16B-chunks
        int p = t + i * 256;
        int r = p >> 3, c8 = p & 7;
        u16x8 u = *(const u16x8*)&qp[(basebs + q0 + r) * H_ + c8 * 8];
        *(u16x8*)&Qs[r][c8 * 8] = u;
    }

    float lsum[4] = {0.f, 0.f, 0.f, 0.f};
    f32x4 o[4] = {};

    for (int kt = 0; kt < KPS / 64; kt++) {
        const int k0 = key0 + kt * 64;
        __syncthreads();                     // prev tile's LDS reads done
        #pragma unroll
        for (int j = 0; j < 2; j++) {        // K tile: 512 chunks
            int p = (w * 2 + j) * 64 + l;
            int r = p >> 3;
            int c8 = (p & 7) ^ (r & 7);
            async16(&kp[(basebs + k0 + r) * H_ + c8 * 8], &Ks[p * 8]);
        }
        #pragma unroll
        for (int j = 0; j < 2; j++) {        // V^T tile: 512 chunks
            int p = (w * 2 + j) * 64 + l;
            int h = p >> 3;
            int c8 = (p & 7) ^ (h & 7);
            async16(&vb[(size_t)h * S_ + k0 + c8 * 8], &Vt[p * 8]);
        }
        float mm[4];
        #pragma unroll
        for (int c = 0; c < 4; c++) mm[c] = mmul[basebs + k0 + c*16 + lrow];
        __syncthreads();                     // drain async queue

        // S = Q K^T (pre-scaled by 1/8 via qp)
        f32x4 s[4] = {};
        #pragma unroll
        for (int kk = 0; kk < 2; kk++) {
            bf16x8 aq = *(const bf16x8*)&Qs[w*16 + lrow][kk*32 + quad*8];
            #pragma unroll
            for (int c = 0; c < 4; c++) {
                const int n = c*16 + lrow;
                bf16x8 bk = *(const bf16x8*)&Ks[(n * 8 + ((kk*4 + quad) ^ (n & 7))) * 8];
                s[c] = __builtin_amdgcn_mfma_f32_16x16x32_bf16(aq, bk, s[c], 0, 0, 0);
            }
        }
        // single-pass softmax numerator; sum deferred
        #pragma unroll
        for (int r = 0; r < 4; r++) {
            float p0 = __expf(s[0][r]) * mm[0];
            float p1 = __expf(s[1][r]) * mm[1];
            float p2 = __expf(s[2][r]) * mm[2];
            float p3 = __expf(s[3][r]) * mm[3];
            lsum[r] += (p0 + p1) + (p2 + p3);
            const int pr = w*16 + quad*4 + r;
            Ps[pr][ 0 + lrow] = f2bf(p0);
            Ps[pr][16 + lrow] = f2bf(p1);
            Ps[pr][32 + lrow] = f2bf(p2);
            Ps[pr][48 + lrow] = f2bf(p3);
        }
        // Ps rows [w*16, w*16+16) wave-local: no barrier needed
        #pragma unroll
        for (int kk = 0; kk < 2; kk++) {
            bf16x8 ap = *(const bf16x8*)&Ps[w*16 + lrow][kk*32 + quad*8];
            #pragma unroll
            for (int c = 0; c < 4; c++) {
                const int h = c*16 + lrow;
                bf16x8 bv = *(const bf16x8*)&Vt[(h * 8 + ((kk*4 + quad) ^ (h & 7))) * 8];
                o[c] = __builtin_amdgcn_mfma_f32_16x16x32_bf16(ap, bv, o[c], 0, 0, 0);
            }
        }
    }

    float* pob = po + (size_t)split * M_ * H_;
    float* plb = pl + (size_t)split * M_;
    #pragma unroll
    for (int r = 0; r < 4; r++) {
        #pragma unroll
        for (int d = 1; d < 16; d <<= 1)
            lsum[r] += __shfl_xor(lsum[r], d, 64);
        const size_t row = basebs + q0 + w*16 + quad*4 + r;
        if (lrow == 0) plb[row] = lsum[r];
        #pragma unroll
        for (int c = 0; c < 4; c++)
            pob[row * H_ + c*16 + lrow] = o[c][r];
    }
}

// out = (sum_s po[s]) / (sum_s pl[s]); one float4 per thread.
__global__ __launch_bounds__(256) void combine_kernel(
    const float* __restrict__ po, const float* __restrict__ pl, float* __restrict__ out)
{
    const int idx = blockIdx.x * 256 + threadIdx.x;
    const size_t row = idx >> 4;
    const int c4 = (idx & 15) * 4;
    float lt = 0.f;
    #pragma unroll
    for (int s = 0; s < SPLIT; s++) lt += pl[(size_t)s * M_ + row];
    f32x4 acc = {};
    #pragma unroll
    for (int s = 0; s < SPLIT; s++) {
        const f32x4 p = *(const f32x4*)&po[((size_t)s * M_ + row) * H_ + c4];
        acc += p;
    }
    const float inv = 1.0f / lt;
    f32x4 r = acc * inv;
    *(f32x4*)&out[row * H_ + c4] = r;
}

extern "C" void kernel_launch(void* const* d_in, const int* in_sizes, int n_in,
                              void* d_out, int out_size, void* d_ws, size_t ws_size,
                              hipStream_t stream) {
    const float* q  = (const float*)d_in[0];
    const float* k  = (const float*)d_in[1];
    const float* v  = (const float*)d_in[2];
    const unsigned char* mask = (const unsigned char*)d_in[3];
    const float* Wq = (const float*)d_in[4];
    const float* Wk = (const float*)d_in[5];
    const float* Wv = (const float*)d_in[6];
    float* out = (float*)d_out;

    unsigned short* qp  = (unsigned short*)d_ws;         // 2 MB
    unsigned short* kp  = qp + (size_t)M_ * H_;          // 2 MB
    unsigned short* vpT = kp + (size_t)M_ * H_;          // 2 MB, [b][h][s]
    float* mmul = (float*)(vpT + (size_t)M_ * H_);       // 64 KB
    unsigned short* Wt = (unsigned short*)(mmul + M_);   // 384 KB
    // pp (proj partials, 25.2 MB) is dead after cproj; attn's po/pl (17 MB)
    // alias the same region.
    float* pp = (float*)(Wt + (size_t)3 * 64 * 1024);    // 25.2 MB
    float* po = pp;                                      // 16.8 MB (alias)
    float* pl = po + (size_t)SPLIT * M_ * H_;            // 256 KB

    wprep_kernel<<<dim3(16, 3), dim3(256), 0, stream>>>(Wq, Wk, Wv, Wt);
    mask_kernel<<<dim3((M_ + 255)/256), dim3(256), 0, stream>>>(mask, mmul, M_);
    proj_kernel<<<dim3(M_/64, 3, SPLITK), dim3(256), 0, stream>>>(q, k, v, Wt, pp);
    cproj_kernel<<<dim3(M_/64, 3), dim3(256), 0, stream>>>(pp, qp, kp, vpT);
    attn_kernel<<<dim3(S_/64, B_, SPLIT), dim3(256), 0, stream>>>(qp, kp, vpT, mmul, po, pl);
    combine_kernel<<<dim3(M_*16/256), dim3(256), 0, stream>>>(po, pl, out);
}